// Round 3
// baseline (659.481 us; speedup 1.0000x reference)
//
#include <hip/hip_runtime.h>
#include <hip/hip_bf16.h>

// Problem constants
#define Mdim 2048
#define Ndim 8192
#define Kdim 8192
#define NT (Kdim / 64)   // 128 K-tiles of BK=64

typedef __bf16 bf16x8 __attribute__((ext_vector_type(8)));
typedef float f32x4 __attribute__((ext_vector_type(4)));
typedef unsigned short ushort4v __attribute__((ext_vector_type(4)));

__device__ __forceinline__ unsigned short f2bf_rne(float f) {
    unsigned u = __float_as_uint(f);
    u += 0x7fffu + ((u >> 16) & 1u);
    return (unsigned short)(u >> 16);
}

// ---------------------------------------------------------------------------
// k_prep: x fp32 -> bf16 only (W dequant is now fused into k_gemm).
// ---------------------------------------------------------------------------
__global__ __launch_bounds__(256) void k_prep(const float* __restrict__ x,
                                              unsigned short* __restrict__ xb) {
    const size_t u = (size_t)blockIdx.x * 256 + threadIdx.x;  // 0..4194303
    float4 a = ((const float4*)x)[u];
    ushort4v o;
    o[0] = f2bf_rne(a.x); o[1] = f2bf_rne(a.y);
    o[2] = f2bf_rne(a.z); o[3] = f2bf_rne(a.w);
    ((ushort4v*)xb)[u] = o;
}

// ---------------------------------------------------------------------------
// Fused 256x256 GEMM with inline 3-bit dequant of B (= W).
//   C[M,N] = A[M,K] * W[N,K]^T, A bf16 (pre-converted), W decoded on the fly.
// B-staging: global packed+codebook -> regs (issued 1 tile ahead at P3),
// v_perm pair-decode -> swizzled ds_write_b128 spread over P1/P2.
// A-staging: global_load_lds (unchanged). Counted-vmcnt pipeline.
// B fragments held in TWO reg sets (bLo/bHi) read phase-ahead, so LB[BUF]
// is never read while decode writes B(T+2) into it (race-free by constr.).
// lgkmcnt(0) before every barrier closes read-in-flight WAR windows.
// vmcnt ledger (per KSTEP; A-stages: Ahi(T+1)@P0 [2], Alo(T+2)@P3 [2];
// B reg-loads for T+3 @P3 [5]):
//   P0: vmcnt(9) forces Ahi(T)  [T<=NT-3; 4 @NT-2; 0 @NT-1]
//   P1: vmcnt(2) forces b5(T+2) + Alo(T+1)   [T<=NT-2]
// Partial forces always cover whole stage-groups -> intra-phase VMEM
// reorder by the scheduler cannot break the ledger.
// ---------------------------------------------------------------------------
__device__ __forceinline__ void gld16(const unsigned short* g, unsigned short* l) {
    __builtin_amdgcn_global_load_lds(
        (const __attribute__((address_space(1))) unsigned int*)g,
        (__attribute__((address_space(3))) unsigned int*)l, 16, 0, 0);
}

#define BAR()    asm volatile("s_barrier" ::: "memory")
#define FENCE()  asm volatile("" ::: "memory")
#define SBAR0()  __builtin_amdgcn_sched_barrier(0)
#define LGKM0()  asm volatile("s_waitcnt lgkmcnt(0)" ::: "memory")
#define VMCNT(n) asm volatile("s_waitcnt vmcnt(" #n ")" ::: "memory")

// Decode one 8-element group (24 payload bits) against bf16-packed codebook
// pairs cP0..cP3 (e1:e0, e3:e2, e5:e4, e7:e6). Returns 4 u32 = 8 bf16.
__device__ __forceinline__ uint4 dec_group(unsigned b, unsigned P0, unsigned P1,
                                           unsigned P2, unsigned P3) {
    uint4 o;
#pragma unroll
    for (int k = 0; k < 4; ++k) {
        unsigned ia = (b >> (6 * k)) & 3u;          // low2 of idx(elem 2k)
        unsigned ib = (b >> (6 * k + 3)) & 3u;      // low2 of idx(elem 2k+1)
        unsigned sel = ia * 0x0202u + 0x01000100u + ((ib * 0x0202u) << 16);
        unsigned lo = __builtin_amdgcn_perm(P1, P0, sel);   // entries 0..3
        unsigned hi = __builtin_amdgcn_perm(P3, P2, sel);   // entries 4..7
        unsigned mA = (unsigned)((int)(b << (29 - 6 * k)) >> 31);  // bit 6k+2
        unsigned mB = (unsigned)((int)(b << (26 - 6 * k)) >> 31);  // bit 6k+5
        unsigned m = (mA & 0xFFFFu) | (mB & 0xFFFF0000u);
        (&o.x)[k] = (hi & m) | (lo & ~m);           // v_bfi
    }
    return o;
}

__global__ __launch_bounds__(512, 2) void k_gemm(const unsigned short* __restrict__ A,
                                                 const int* __restrict__ packed,
                                                 const float* __restrict__ cb,
                                                 float* __restrict__ C) {
    __shared__ unsigned short LA[4 * 8192];   // [buf][half][128*64] = 64 KB
    __shared__ unsigned short LB[4 * 8192];   // 64 KB (decoded W)

    const int tid  = threadIdx.x;
    const int lane = tid & 63;
    const int wave = tid >> 6;               // 0..7
    const int qm = wave >> 2;                // 0..1
    const int qn = wave & 3;                 // 0..3

    const int bid = blockIdx.x;
    const int bm = (bid & 7) * 256;          // XCD-resident A panel
    const int bn = (bid >> 3) * 256;

    // ---- A staging (global_load_lds, pre-swizzled source) ----
    const int chunk0 = tid, chunk1 = tid + 512;
    const int srow0 = chunk0 >> 3, srow1 = chunk1 >> 3;
    const int scol0 = ((chunk0 & 7) ^ (srow0 & 7)) * 8;
    const int scol1 = ((chunk1 & 7) ^ (srow1 & 7)) * 8;
    const unsigned short* Ag0 = A + (size_t)(bm + srow0) * Kdim + scol0;
    const unsigned short* Ag1 = A + (size_t)(bm + srow1) * Kdim + scol1;

#define STAGE_A(T, H, BUF) do {                                                   \
    unsigned short* _d = LA + ((BUF) * 2 + (H)) * 8192;                           \
    gld16(Ag0 + (size_t)(H) * 128 * Kdim + (size_t)(T) * 64, _d + (size_t)tid * 8);        \
    gld16(Ag1 + (size_t)(H) * 128 * Kdim + (size_t)(T) * 64, _d + (size_t)(tid + 512) * 8);\
    FENCE();                                                                      \
} while (0)

    // ---- B decode addressing: 2 threads per row, 32 elems (4 groups) each ----
    const int drow  = tid >> 1;              // 0..255 (panel row)
    const int dp    = tid & 1;               // 0/1: elems [32p,32p+32)
    const int dhalf = drow >> 7;             // LDS half
    const int drr   = drow & 127;            // row within half
    const int drlo  = drr & 7;               // swizzle key
    const int dp4   = dp * 4;                // chunk base
    const int nrow  = bn + drow;
    const int* Pg   = packed + (size_t)nrow * 3072 + dp * 12;   // int32 units
    const float* Cg = cb + (size_t)nrow * 512;

    int4 bq0, bq1, bq2;          // packed payload for tile T+2 (in flight)
    float4 bc0, bc1;             // codebook block for tile T+2
    unsigned cP0, cP1, cP2, cP3; // bf16-packed codebook pairs

#define B_ISSUE(T3) do {                                                          \
    const int4* _pp = (const int4*)(Pg + (size_t)(T3) * 24);                      \
    bq0 = _pp[0]; bq1 = _pp[1]; bq2 = _pp[2];                                     \
    const float4* _cp = (const float4*)(Cg + ((T3) >> 1) * 8);                    \
    bc0 = _cp[0]; bc1 = _cp[1];                                                   \
} while (0)

#define CVT_CP(CC0, CC1) do {                                                     \
    cP0 = (unsigned)f2bf_rne(CC0.x) | ((unsigned)f2bf_rne(CC0.y) << 16);          \
    cP1 = (unsigned)f2bf_rne(CC0.z) | ((unsigned)f2bf_rne(CC0.w) << 16);          \
    cP2 = (unsigned)f2bf_rne(CC1.x) | ((unsigned)f2bf_rne(CC1.y) << 16);          \
    cP3 = (unsigned)f2bf_rne(CC1.z) | ((unsigned)f2bf_rne(CC1.w) << 16);          \
} while (0)

// Decode group G (words W0,W1,W2) and write its 16B chunk (swizzled) to LB[BUF].
#define DECODE_G(G, W0, W1, W2, BUF) do {                                         \
    unsigned _b = (unsigned)(W0) | ((unsigned)(W1) << 8) | ((unsigned)(W2) << 16);\
    uint4 _o = dec_group(_b, cP0, cP1, cP2, cP3);                                 \
    int _c = (dp4 + (G)) ^ drlo;                                                  \
    *(uint4*)&LB[((BUF) * 2 + dhalf) * 8192 + drr * 64 + (_c << 3)] = _o;         \
} while (0)

    // ---- fragment read addressing (swizzled) ----
    const int r15 = lane & 15;
    const int q   = lane >> 4;
    const int rlo = r15 & 7;
    const int aro = qm * 64 + r15;
    const int bro = qn * 32 + r15;
    const int ch0 = ((0 + q) ^ rlo) * 8;
    const int ch1 = ((4 + q) ^ rlo) * 8;

    f32x4 acc[4][4][2];
    const f32x4 zero = {0.f, 0.f, 0.f, 0.f};
#pragma unroll
    for (int p = 0; p < 4; ++p)
#pragma unroll
        for (int i = 0; i < 4; ++i)
#pragma unroll
            for (int j = 0; j < 2; ++j) acc[p][i][j] = zero;

    bf16x8 aF[4][2];     // A: lo (P0,P1) then hi (P2,P3), reg-reused
    bf16x8 bLo[2][2];    // B lo half (P0,P3)
    bf16x8 bHi[2][2];    // B hi half (P1,P2)

#define LOAD_AF(BUF, H) do {                                                      \
    const unsigned short* _s = LA + ((BUF) * 2 + (H)) * 8192;                     \
    _Pragma("unroll") for (int i = 0; i < 4; ++i) {                               \
        int _r = (aro + i * 16) * 64;                                             \
        aF[i][0] = *(const bf16x8*)&_s[_r + ch0];                                 \
        aF[i][1] = *(const bf16x8*)&_s[_r + ch1];                                 \
    }                                                                             \
} while (0)
#define LOAD_BF(SET, BUF, H) do {                                                 \
    const unsigned short* _s = LB + ((BUF) * 2 + (H)) * 8192;                     \
    _Pragma("unroll") for (int j = 0; j < 2; ++j) {                               \
        int _r = (bro + j * 16) * 64;                                             \
        SET[j][0] = *(const bf16x8*)&_s[_r + ch0];                                \
        SET[j][1] = *(const bf16x8*)&_s[_r + ch1];                                \
    }                                                                             \
} while (0)

#define MFMA_PH(P, SET) do {                                                      \
    __builtin_amdgcn_s_setprio(1);                                                \
    _Pragma("unroll") for (int i = 0; i < 4; ++i)                                 \
    _Pragma("unroll") for (int j = 0; j < 2; ++j) {                               \
        acc[P][i][j] = __builtin_amdgcn_mfma_f32_16x16x32_bf16(                   \
            aF[i][0], SET[j][0], acc[P][i][j], 0, 0, 0);                          \
        acc[P][i][j] = __builtin_amdgcn_mfma_f32_16x16x32_bf16(                   \
            aF[i][1], SET[j][1], acc[P][i][j], 0, 0, 0);                          \
    }                                                                             \
    __builtin_amdgcn_s_setprio(0);                                                \
} while (0)

// Phases: P0 = (Alo,Blo), P1 = (Alo,Bhi), P2 = (Ahi,Bhi), P3 = (Ahi,Blo).
#define KSTEP(T, BUF) do {                                                        \
    /* P0 */                                                                      \
    if ((T) + 1 < NT) STAGE_A((T) + 1, 1, (BUF) ^ 1);                             \
    if ((T) + 2 < NT)      { VMCNT(9); }                                          \
    else if ((T) + 1 < NT) { VMCNT(4); }                                          \
    else                   { VMCNT(0); }                                          \
    MFMA_PH(0, bLo);                                                              \
    SBAR0();                                                                      \
    LOAD_BF(bHi, BUF, 1);          /* Bhi(T) for P1,P2 */                         \
    LGKM0(); BAR();                                                               \
    /* P1 */                                                                      \
    if ((T) + 1 < NT) VMCNT(2);                                                   \
    MFMA_PH(1, bHi);                                                              \
    if ((T) + 2 < NT) {                                                           \
        CVT_CP(bc0, bc1);                                                         \
        DECODE_G(0, bq0.x, bq0.y, bq0.z, BUF);                                    \
        DECODE_G(1, bq0.w, bq1.x, bq1.y, BUF);                                    \
    }                                                                             \
    SBAR0();                                                                      \
    LOAD_AF(BUF, 1);               /* Ahi(T) for P2,P3 */                         \
    LGKM0(); BAR();                                                               \
    /* P2 */                                                                      \
    MFMA_PH(2, bHi);                                                              \
    if ((T) + 2 < NT) {                                                           \
        DECODE_G(2, bq1.z, bq1.w, bq2.x, BUF);                                    \
        DECODE_G(3, bq2.y, bq2.z, bq2.w, BUF);                                    \
    }                                                                             \
    LGKM0(); BAR();                                                               \
    /* P3 */                                                                      \
    MFMA_PH(3, bLo);                                                              \
    if ((T) + 2 < NT) STAGE_A((T) + 2, 0, BUF);                                   \
    if ((T) + 3 < NT) B_ISSUE((T) + 3);                                           \
    SBAR0();                                                                      \
    if ((T) + 1 < NT) { LOAD_AF((BUF) ^ 1, 0); LOAD_BF(bLo, (BUF) ^ 1, 0); }      \
    LGKM0(); BAR();                                                               \
} while (0)

    // ---- Prologue ----
    STAGE_A(0, 0, 0); STAGE_A(0, 1, 0); STAGE_A(1, 0, 1);   // 6 gld16
    // Decode B(0) -> LB[0], B(1) -> LB[1] (plain loads; compiler waits).
#pragma unroll
    for (int tt = 0; tt < 2; ++tt) {
        const int4* pp = (const int4*)(Pg + (size_t)tt * 24);
        int4 w0 = pp[0], w1 = pp[1], w2 = pp[2];
        const float4* cp = (const float4*)(Cg);   // (tt>>1)==0 for tt in {0,1}
        float4 c0 = cp[0], c1 = cp[1];
        CVT_CP(c0, c1);
        DECODE_G(0, w0.x, w0.y, w0.z, tt);
        DECODE_G(1, w0.w, w1.x, w1.y, tt);
        DECODE_G(2, w1.z, w1.w, w2.x, tt);
        DECODE_G(3, w2.y, w2.z, w2.w, tt);
    }
    B_ISSUE(2);                 // 5 loads left in flight across the barrier
    VMCNT(5);                   // force all 6 gld16 (A0 both halves, A1 lo)
    LGKM0(); BAR();
    LOAD_AF(0, 0);              // Alo(0)
    LOAD_BF(bLo, 0, 0);         // Blo(0)

    for (int t2 = 0; t2 < NT; t2 += 2) {
        KSTEP(t2, 0);
        KSTEP(t2 + 1, 1);
    }

    // ---- Epilogue: C/D layout col = lane&15, row = (lane>>4)*4 + r ----
    constexpr int RHs[4] = {0, 0, 1, 1};
    constexpr int CHs[4] = {0, 1, 1, 0};
#pragma unroll
    for (int p = 0; p < 4; ++p) {
#pragma unroll
        for (int i = 0; i < 4; ++i) {
#pragma unroll
            for (int j = 0; j < 2; ++j) {
                int row = bm + RHs[p] * 128 + qm * 64 + i * 16 + q * 4;
                int col = bn + CHs[p] * 128 + qn * 32 + j * 16 + r15;
                float* outp = C + (size_t)row * Ndim + col;
#pragma unroll
                for (int r = 0; r < 4; ++r)
                    outp[(size_t)r * Ndim] = acc[p][i][j][r];
            }
        }
    }

#undef STAGE_A
#undef B_ISSUE
#undef CVT_CP
#undef DECODE_G
#undef LOAD_AF
#undef LOAD_BF
#undef MFMA_PH
#undef KSTEP
}

// ---------------------------------------------------------------------------
extern "C" void kernel_launch(void* const* d_in, const int* in_sizes, int n_in,
                              void* d_out, int out_size, void* d_ws, size_t ws_size,
                              hipStream_t stream) {
    const float* x      = (const float*)d_in[0];   // 2048 x 8192 fp32
    const int*   packed = (const int*)d_in[1];     // 25165824 int32 (one byte each)
    const float* cb     = (const float*)d_in[2];   // 524288 x 8 fp32
    float* out = (float*)d_out;                    // 2048 x 8192 fp32

    unsigned short* Xb = (unsigned short*)d_ws;    // 32 MB bf16 x

    // 1) x fp32 -> bf16 (W dequant is fused into the GEMM)
    k_prep<<<16384, 256, 0, stream>>>(x, Xb);
    // 2) fused dequant + GEMM: 256 blocks (1/CU), 512 threads, 128 KB LDS
    k_gemm<<<dim3(256), 512, 0, stream>>>(Xb, packed, cb, out);
}